// Round 10
// baseline (304.521 us; speedup 1.0000x reference)
//
#include <hip/hip_runtime.h>
#include <hip/hip_bf16.h>
#include <stdint.h>

// ---------------------------------------------------------------------------
// MetaMultiHeadSelfAttention: B=4, S=2048, D=1024, H=16, hd=64, causal.
// R17:
//   1. attn7: 4 waves x 64 Q-rows/wave (256-row blocks, 512 unpaired) --
//      2x MFMA per wave-tile with attn4's exact proven staging ring
//      (triple buffer, counted vmcnt(4), 2-tile lead). P is mt-serial in a
//      16-row wave-private LDS buffer (plain C accesses -> compiler-ordered).
//      LDS 57.2 KB -> 2 blocks/CU; decode pairs co-resident blocks
//      (bid, bid+256) with complementary qb -> uniform 36 tiles per slot;
//      XCD grouping per (h,b) preserved.
//   2. QK-proj and V^T-proj merged into ONE 768-block launch (3 exact
//      rounds, branch selects operands) -- removes a launch boundary.
// O-proj + cvt unchanged from R14/R16 (passed, absmax 0.015625).
// ---------------------------------------------------------------------------

typedef __bf16 bf16x8 __attribute__((ext_vector_type(8)));
typedef __bf16 bf16x4 __attribute__((ext_vector_type(4)));
typedef float  f32x4  __attribute__((ext_vector_type(4)));

static __device__ __forceinline__ f32x4 mfma16(bf16x8 a, bf16x8 b, f32x4 c) {
  return __builtin_amdgcn_mfma_f32_16x16x32_bf16(a, b, c, 0, 0, 0);
}

// async 16B/lane global->LDS; LDS dest = wave-uniform base + lane*16
static __device__ __forceinline__ void load16_lds(const void* g, void* l) {
  __builtin_amdgcn_global_load_lds(
      (const __attribute__((address_space(1))) unsigned int*)g,
      (__attribute__((address_space(3))) unsigned int*)l, 16, 0, 0);
}

// ---------------------------------------------------------------------------
// fused cvt: blocks [0,4096) convert x (fp32->bf16, 8/thread);
// blocks [4096,6144) convert weights: wq (scaled by 0.125*log2e) -> wqk[0],
// wk -> wqk[1MB], wv -> wvb, wo -> wob.
// ---------------------------------------------------------------------------
__global__ __launch_bounds__(256) void cvt_all(
    const float* __restrict__ x,
    const float* __restrict__ w0, const float* __restrict__ w1,
    const float* __restrict__ w2, const float* __restrict__ w3,
    __bf16* __restrict__ xb, __bf16* __restrict__ wqk,
    __bf16* __restrict__ wvb, __bf16* __restrict__ wob) {
  const int blk = blockIdx.x;
  const int t = threadIdx.x;
  if (blk < 4096) {
    int i = blk * 256 + t;
    const float4* in4 = (const float4*)x;
    float4 a = in4[2 * i], b = in4[2 * i + 1];
    __bf16 v[8];
    v[0] = (__bf16)a.x; v[1] = (__bf16)a.y; v[2] = (__bf16)a.z; v[3] = (__bf16)a.w;
    v[4] = (__bf16)b.x; v[5] = (__bf16)b.y; v[6] = (__bf16)b.z; v[7] = (__bf16)b.w;
    *(bf16x8*)(xb + 8 * i) = *(bf16x8*)v;
  } else {
    int b2 = blk - 4096;               // 2048 blocks, 512 per matrix
    int m = b2 >> 9;
    const float* src = (m == 0) ? w0 : (m == 1) ? w1 : (m == 2) ? w2 : w3;
    __bf16* dst = (m == 0) ? wqk : (m == 1) ? (wqk + (size_t)(1024 * 1024))
                : (m == 2) ? wvb : wob;
    const float scl = (m == 0) ? 0.18033688011112042f : 1.0f;  // 0.125*log2(e)
    int i = (b2 & 511) * 256 + t;
    const float4* in4 = (const float4*)src;
    float4 a = in4[2 * i], b = in4[2 * i + 1];
    __bf16 v[8];
    v[0] = (__bf16)(a.x * scl); v[1] = (__bf16)(a.y * scl);
    v[2] = (__bf16)(a.z * scl); v[3] = (__bf16)(a.w * scl);
    v[4] = (__bf16)(b.x * scl); v[5] = (__bf16)(b.y * scl);
    v[6] = (__bf16)(b.z * scl); v[7] = (__bf16)(b.w * scl);
    *(bf16x8*)(dst + 8 * i) = *(bf16x8*)v;
  }
}

// ---------------------------------------------------------------------------
// stage unit: 64 rows x 64 cols bf16 (8 KB) = 1 global_load_lds / thread
// (512-thread kernels), chunk-XOR swizzle (16B chunk c of row r -> c^(r&7)).
// ---------------------------------------------------------------------------
static __device__ __forceinline__ void stage_unit(
    const __bf16* __restrict__ X, long grow0, int K, long k0,
    __bf16* lds, int t) {
  const int lane = t & 63, w = t >> 6;
  const int rl = w * 8 + (lane >> 3);                   // row within unit
  const int chunk = (lane & 7) ^ ((lane >> 3) & 7);     // row&7 == (lane>>3)&7
  load16_lds(X + (grow0 + rl) * (long)K + k0 + chunk * 8,
             lds + (w * 8) * 64);                       // wave-uniform base
}

// ---------------------------------------------------------------------------
// 256x128 triple-buffered 2-phase GEMM core (R10, harness-verified).
// Templated body shared by gemm_dual (bf16 out) and gemm_bt8 (float out).
// ---------------------------------------------------------------------------
template <typename OutT>
static __device__ __forceinline__ void gemm_core(
    const __bf16* __restrict__ A, const __bf16* __restrict__ Bw,
    OutT* __restrict__ C, int N, int K, long m0, long n0, int t) {
  __shared__ __align__(16) __bf16 As[3][256 * 64];
  __shared__ __align__(16) __bf16 Bs[3][128 * 64];
  const int lane = t & 63, w = t >> 6;
  const int wm = w >> 1, wn = w & 1;        // 4M x 2N waves
  const int l15 = lane & 15, quad = lane >> 4;

  int aoff[4][2], boff[4][2];
#pragma unroll
  for (int mf = 0; mf < 4; mf++)
#pragma unroll
    for (int ks = 0; ks < 2; ks++)
      aoff[mf][ks] = (wm * 64 + mf * 16 + l15) * 64 + (((ks * 4 + quad) ^ (l15 & 7)) << 3);
#pragma unroll
  for (int nf = 0; nf < 4; nf++)
#pragma unroll
    for (int ks = 0; ks < 2; ks++)
      boff[nf][ks] = (wn * 64 + nf * 16 + l15) * 64 + (((ks * 4 + quad) ^ (l15 & 7)) << 3);

  const int NT = K >> 6;
  __bf16 *Ac = As[0], *An = As[1], *Asg = As[2];
  __bf16 *Bc = Bs[0], *Bn = Bs[1], *Bsg = Bs[2];

#pragma unroll
  for (int u = 0; u < 4; u++) stage_unit(A, m0 + u * 64, K, 0, Ac + u * 64 * 64, t);
#pragma unroll
  for (int u = 0; u < 2; u++) stage_unit(Bw, n0 + u * 64, K, 0, Bc + u * 64 * 64, t);
#pragma unroll
  for (int u = 0; u < 4; u++) stage_unit(A, m0 + u * 64, K, 64, An + u * 64 * 64, t);
#pragma unroll
  for (int u = 0; u < 2; u++) stage_unit(Bw, n0 + u * 64, K, 64, Bn + u * 64 * 64, t);
  asm volatile("s_waitcnt vmcnt(6)" ::: "memory");
  __builtin_amdgcn_s_barrier();

  f32x4 acc[4][4] = {};
  for (int T = 0; T < NT; T++) {
    const bool pf2 = (T + 2 < NT);
    const long kn2 = (long)(T + 2) * 64;

    bf16x8 bfr[4][2];
#pragma unroll
    for (int nf = 0; nf < 4; nf++)
#pragma unroll
      for (int ks = 0; ks < 2; ks++)
        bfr[nf][ks] = *(const bf16x8*)(Bc + boff[nf][ks]);
    {
      bf16x8 a00 = *(const bf16x8*)(Ac + aoff[0][0]);
      bf16x8 a01 = *(const bf16x8*)(Ac + aoff[0][1]);
      bf16x8 a10 = *(const bf16x8*)(Ac + aoff[1][0]);
      bf16x8 a11 = *(const bf16x8*)(Ac + aoff[1][1]);
      if (pf2) {
#pragma unroll
        for (int u = 0; u < 4; u++)
          stage_unit(A, m0 + u * 64, K, kn2, Asg + u * 64 * 64, t);
      }
      __builtin_amdgcn_s_barrier();
      asm volatile("s_waitcnt lgkmcnt(0)" ::: "memory");
      __builtin_amdgcn_sched_barrier(0);
      __builtin_amdgcn_s_setprio(1);
#pragma unroll
      for (int nf = 0; nf < 4; nf++) {
        acc[0][nf] = mfma16(a00, bfr[nf][0], acc[0][nf]);
        acc[0][nf] = mfma16(a01, bfr[nf][1], acc[0][nf]);
        acc[1][nf] = mfma16(a10, bfr[nf][0], acc[1][nf]);
        acc[1][nf] = mfma16(a11, bfr[nf][1], acc[1][nf]);
      }
      __builtin_amdgcn_s_setprio(0);
      __builtin_amdgcn_s_barrier();
    }
    {
      bf16x8 a00 = *(const bf16x8*)(Ac + aoff[2][0]);
      bf16x8 a01 = *(const bf16x8*)(Ac + aoff[2][1]);
      bf16x8 a10 = *(const bf16x8*)(Ac + aoff[3][0]);
      bf16x8 a11 = *(const bf16x8*)(Ac + aoff[3][1]);
      if (pf2) {
#pragma unroll
        for (int u = 0; u < 2; u++)
          stage_unit(Bw, n0 + u * 64, K, kn2, Bsg + u * 64 * 64, t);
        asm volatile("s_waitcnt vmcnt(6)" ::: "memory");
      } else {
        asm volatile("s_waitcnt vmcnt(0)" ::: "memory");
      }
      __builtin_amdgcn_s_barrier();
      asm volatile("s_waitcnt lgkmcnt(0)" ::: "memory");
      __builtin_amdgcn_sched_barrier(0);
      __builtin_amdgcn_s_setprio(1);
#pragma unroll
      for (int nf = 0; nf < 4; nf++) {
        acc[2][nf] = mfma16(a00, bfr[nf][0], acc[2][nf]);
        acc[2][nf] = mfma16(a01, bfr[nf][1], acc[2][nf]);
        acc[3][nf] = mfma16(a10, bfr[nf][0], acc[3][nf]);
        acc[3][nf] = mfma16(a11, bfr[nf][1], acc[3][nf]);
      }
      __builtin_amdgcn_s_setprio(0);
      __builtin_amdgcn_s_barrier();
    }
    __bf16* ta = Ac; Ac = An; An = Asg; Asg = ta;
    __bf16* tb = Bc; Bc = Bn; Bn = Bsg; Bsg = tb;
  }

#pragma unroll
  for (int mf = 0; mf < 4; mf++)
#pragma unroll
    for (int nf = 0; nf < 4; nf++)
#pragma unroll
      for (int r = 0; r < 4; r++) {
        long row = m0 + wm * 64 + mf * 16 + quad * 4 + r;
        long col = n0 + wn * 64 + nf * 16 + l15;
        float v = acc[mf][nf][r];
        if constexpr (sizeof(OutT) == 2) C[row * (long)N + col] = (OutT)(__bf16)v;
        else                             C[row * (long)N + col] = v;
      }
}

// merged QK-proj (512 tiles) + V^T-proj (256 tiles): 768 blocks = 3 rounds
__global__ __launch_bounds__(512, 2) void gemm_dual(
    const __bf16* __restrict__ xb, const __bf16* __restrict__ wqk,
    const __bf16* __restrict__ wvb,
    __bf16* __restrict__ QK, __bf16* __restrict__ VTg) {
  const int bid = blockIdx.x;
  const int swz = (bid & 7) * 96 + (bid >> 3);   // bijective over 768
  if (swz < 512) {
    gemm_core<__bf16>(xb, wqk, QK, 2048, 1024,
                      (long)(swz / 16) * 256, (long)(swz % 16) * 128, threadIdx.x);
  } else {
    const int s = swz - 512;
    gemm_core<__bf16>(wvb, xb, VTg, 8192, 1024,
                      (long)(s / 64) * 256, (long)(s % 64) * 128, threadIdx.x);
  }
}

// O-projection (fp32 out), 256 blocks = 1 exact round
__global__ __launch_bounds__(512, 2) void gemm_bt8(
    const __bf16* __restrict__ A, const __bf16* __restrict__ Bw,
    float* __restrict__ C, int M, int N, int K, int NX) {
  const int bid = blockIdx.x;
  const int cpx = gridDim.x >> 3;
  const int swz = (bid & 7) * cpx + (bid >> 3);
  gemm_core<float>(A, Bw, C, N, K, (long)(swz / NX) * 256, (long)(swz % NX) * 128,
                   threadIdx.x);
}

// ---------------------------------------------------------------------------
// Causal attention, R17 (attn7): 4 waves x 64 Q-rows, 256-row blocks,
// 512 unpaired blocks (co-resident pairs have complementary qb -> uniform
// 36 tiles/slot). attn4's staging ring verbatim: triple-buffered K/VT,
// 4 loads/thread/tile, counted vmcnt(4), 2-tile lead. P mt-serial in a
// 16-row wave-private buffer (plain C LDS ops). exp2, ones-column l.
// ---------------------------------------------------------------------------
__global__ __launch_bounds__(256) void attn7(
    const __bf16* __restrict__ QK, const __bf16* __restrict__ VT,
    __bf16* __restrict__ O) {
  constexpr int SD = 2048;
  constexpr int LDP = 72;
  __shared__ __align__(16) __bf16 Ks[3][64 * 64];
  __shared__ __align__(16) __bf16 Vs[3][64 * 64];
  __shared__ __align__(16) __bf16 Pw[4 * 16 * LDP];
  const int t = threadIdx.x;
  const int lane = t & 63, w = t >> 6;      // 4 waves
  const int l15 = lane & 15, quad = lane >> 4;

  // decode: a=bid&7 (XCD), m3=(bid>>3)&7, c=(bid>>6)&3, hi=bid>>8.
  // g = a*8 + c*2 + hi (h,b group; a = g>>3 fixed per group -> XCD-local).
  // qb = hi ? 7-m3 : m3  ->  blocks bid and bid+256 have complementary qb.
  const int bid = blockIdx.x;
  const int a = bid & 7, m3 = (bid >> 3) & 7, c = (bid >> 6) & 3, hi = bid >> 8;
  const int g = a * 8 + c * 2 + hi;
  const int qb = hi ? (7 - m3) : m3;
  const int h = g & 15, b = g >> 4;

  const long qbase = (long)b * 2048 * SD + h * 64;
  const long kbase = qbase + 1024;
  __bf16* Pme = Pw + w * 16 * LDP;

  // staging (attn4 scheme): wave w rows [w*16, w*16+16) via 2 insts of 8 rows
  const int sr = w * 16 + (lane >> 3);
  const int scg = (lane & 7) ^ (sr & 7);
  const int ldsOff = (w * 16) * 64;
  const __bf16* gK = QK + kbase + (long)sr * SD + scg * 8;
  const __bf16* gV = VT + (long)(h * 64 + sr) * 8192 + b * 2048 + scg * 8;

  int kvoff[4][2];
#pragma unroll
  for (int nt = 0; nt < 4; nt++)
#pragma unroll
    for (int kk = 0; kk < 2; kk++)
      kvoff[nt][kk] = (nt * 16 + l15) * 64 + (((kk * 4 + quad) ^ (l15 & 7)) << 3);

  bf16x8 ones;
#pragma unroll
  for (int j = 0; j < 8; j++) ones[j] = (__bf16)1.0f;

  const int q0 = qb * 256;
  const int wrow0 = q0 + w * 64;            // wave owns 64 rows

  // Q fragments: 4 mt x 2 kk
  bf16x8 qf[4][2];
#pragma unroll
  for (int mt = 0; mt < 4; mt++)
#pragma unroll
    for (int kk = 0; kk < 2; kk++)
      qf[mt][kk] = *(const bf16x8*)(QK + qbase +
          (long)(wrow0 + mt * 16 + l15) * SD + kk * 32 + quad * 8);

  f32x4 o_acc[4][4] = {};
  f32x4 o_l[4] = {};

  const int nkt = 4 * qb + 4;               // >= 4

  // prologue: stage tiles 0,1 (8 loads)
  load16_lds(gK, Ks[0] + ldsOff);
  load16_lds(gK + 8 * SD, Ks[0] + ldsOff + 8 * 64);
  load16_lds(gV, Vs[0] + ldsOff);
  load16_lds(gV + 8 * 8192, Vs[0] + ldsOff + 8 * 64);
  {
    const __bf16* gK1 = gK + (long)64 * SD;
    const __bf16* gV1 = gV + 64;
    load16_lds(gK1, Ks[1] + ldsOff);
    load16_lds(gK1 + 8 * SD, Ks[1] + ldsOff + 8 * 64);
    load16_lds(gV1, Vs[1] + ldsOff);
    load16_lds(gV1 + 8 * 8192, Vs[1] + ldsOff + 8 * 64);
  }

  int cur = 0;
  for (int kt = 0; kt < nkt; kt++) {
    if (kt + 1 < nkt) asm volatile("s_waitcnt vmcnt(4)" ::: "memory");
    else              asm volatile("s_waitcnt vmcnt(0)" ::: "memory");
    __builtin_amdgcn_s_barrier();
    __builtin_amdgcn_sched_barrier(0);

    if (kt + 2 < nkt) {   // prefetch kt+2 into buf (cur+2)%3 (dead)
      int stg = cur + 2; if (stg >= 3) stg -= 3;
      const __bf16* gKn = gK + (long)(kt + 2) * 64 * SD;
      const __bf16* gVn = gV + (kt + 2) * 64;
      load16_lds(gKn, Ks[stg] + ldsOff);
      load16_lds(gKn + 8 * SD, Ks[stg] + ldsOff + 8 * 64);
      load16_lds(gVn, Vs[stg] + ldsOff);
      load16_lds(gVn + 8 * 8192, Vs[stg] + ldsOff + 8 * 64);
    }

    const int k0 = kt * 64;
    if (k0 <= wrow0 + 63) {                 // wave has live rows in this tile
      const __bf16* KsB = Ks[cur];
      const __bf16* VsB = Vs[cur];
      bf16x8 kf[4][2], vf[4][2];
#pragma unroll
      for (int nt = 0; nt < 4; nt++)
#pragma unroll
        for (int kk = 0; kk < 2; kk++) {
          kf[nt][kk] = *(const bf16x8*)(KsB + kvoff[nt][kk]);
          vf[nt][kk] = *(const bf16x8*)(VsB + kvoff[nt][kk]);
        }

#pragma unroll
      for (int mt = 0; mt < 4; mt++) {
        const int qlo = wrow0 + mt * 16;
        if (k0 > qlo + 15) continue;        // all keys masked for these rows

        // S^T = K Q^T for this mt: lane holds key = nt*16+quad*4+r, qrow=l15
        f32x4 st[4];
        __builtin_amdgcn_s_setprio(1);
#pragma unroll
        for (int nt = 0; nt < 4; nt++) {
          f32x4 z = {0.f, 0.f, 0.f, 0.f};
          z = mfma16(kf[nt][0], qf[mt][0], z);
          st[nt] = mfma16(kf[nt][1], qf[mt][1], z);
        }
        __builtin_amdgcn_s_setprio(0);

        // P = exp2(S); 16-row wave-private buffer (rows = l15)
        if (k0 + 63 <= qlo) {               // fully unmasked
#pragma unroll
          for (int nt = 0; nt < 4; nt++) {
            bf16x4 pb;
#pragma unroll
            for (int r = 0; r < 4; r++)
              pb[r] = (__bf16)__builtin_amdgcn_exp2f(st[nt][r]);
            *(bf16x4*)(Pme + l15 * LDP + nt * 16 + quad * 4) = pb;
          }
        } else {                            // diagonal: causal mask
          const int qrow = qlo + l15;
#pragma unroll
          for (int nt = 0; nt < 4; nt++) {
            const int keyb = k0 + nt * 16 + quad * 4;
            bf16x4 pb;
#pragma unroll
            for (int r = 0; r < 4; r++) {
              float e = __builtin_amdgcn_exp2f(st[nt][r]);
              if (keyb + r > qrow) e = 0.f;
              pb[r] = (__bf16)e;
            }
            *(bf16x4*)(Pme + l15 * LDP + nt * 16 + quad * 4) = pb;
          }
        }

        // PV for this mt (compiler orders the P RAW/WAR through LDS)
#pragma unroll
        for (int kk = 0; kk < 2; kk++) {
          bf16x8 pf = *(const bf16x8*)(Pme + l15 * LDP + kk * 32 + quad * 8);
          __builtin_amdgcn_s_setprio(1);
#pragma unroll
          for (int dt = 0; dt < 4; dt++)
            o_acc[mt][dt] = mfma16(pf, vf[dt][kk], o_acc[mt][dt]);
          o_l[mt] = mfma16(pf, ones, o_l[mt]);
          __builtin_amdgcn_s_setprio(0);
        }
      }
    }
    cur = (cur == 2) ? 0 : cur + 1;
  }

  // epilogue: o_l holds per-row l in the exact o_acc row layout
#pragma unroll
  for (int mt = 0; mt < 4; mt++) {
#pragma unroll
    for (int r = 0; r < 4; r++) {
      float inv = 1.f / o_l[mt][r];
      int row = wrow0 + mt * 16 + quad * 4 + r;
      long ob = ((long)b * 2048 + row) * 1024 + h * 64;
#pragma unroll
      for (int dt = 0; dt < 4; dt++)
        O[ob + dt * 16 + l15] = (__bf16)(o_acc[mt][dt][r] * inv);
    }
  }
}

// ---------------------------------------------------------------------------
extern "C" void kernel_launch(void* const* d_in, const int* in_sizes, int n_in,
                              void* d_out, int out_size, void* d_ws, size_t ws_size,
                              hipStream_t stream) {
  const float* x  = (const float*)d_in[0];
  const float* wq = (const float*)d_in[1];
  const float* wk = (const float*)d_in[2];
  const float* wv = (const float*)d_in[3];
  const float* wo = (const float*)d_in[4];
  float* out = (float*)d_out;

  char* ws = (char*)d_ws;
  __bf16* xb   = (__bf16*)(ws);               // 16 MB [8192,1024]; reused as Ab
  __bf16* wqk  = (__bf16*)(ws + (16l << 20)); //  4 MB [2048,1024] (wq,wk)
  __bf16* wvb  = (__bf16*)(ws + (20l << 20)); //  2 MB [1024,1024]
  __bf16* wob  = (__bf16*)(ws + (22l << 20)); //  2 MB [1024,1024]
  __bf16* QK   = (__bf16*)(ws + (24l << 20)); // 32 MB [8192,2048]
  __bf16* VTg  = (__bf16*)(ws + (56l << 20)); // 16 MB [1024,8192] -> 72 MB total
  __bf16* Ab   = xb;                          // x dead after both input gemms

  // fused conversions (x + all 4 weights), one launch
  cvt_all<<<6144, 256, 0, stream>>>(x, wq, wk, wv, wo, xb, wqk, wvb, wob);

  // merged QK projection + V^T projection (768 blocks = 3 exact rounds)
  gemm_dual<<<768, 512, 0, stream>>>(xb, wqk, wvb, QK, VTg);

  // causal attention (512 blocks x 256 threads, 256-row tiles) -> Ab
  attn7<<<512, 256, 0, stream>>>(QK, VTg, Ab);

  // output projection (fp32 out)              (32x8 = 256 blocks, 1 exact round)
  gemm_bt8<<<256, 512, 0, stream>>>(Ab, wob, out, 8192, 1024, 1024, 8);
}

// Round 11
// 226.401 us; speedup vs baseline: 1.3450x; 1.3450x over previous
//
#include <hip/hip_runtime.h>
#include <hip/hip_bf16.h>
#include <stdint.h>

// ---------------------------------------------------------------------------
// MetaMultiHeadSelfAttention: B=4, S=2048, D=1024, H=16, hd=64, causal.
// R18: consolidation of verified-best pieces after attn7's regression:
//   - attn6 (R16, 62.1 us): 8 waves/512 threads, paired 256-row halves
//     (qb, 7-qb) -> uniform 36 tiles; triple-buffered K/VT, counted
//     vmcnt(2) with 2-tile lead; XCD grouping; exp2; ones-column l.
//   - gemm_dual (R17, neutral-to-better): QK-proj + V^T-proj in ONE
//     768-block launch (3 exact rounds of the R10 256x128 core).
//   - O-proj gemm_core<float> (256 blocks = 1 round), cvt_all: unchanged.
// ---------------------------------------------------------------------------

typedef __bf16 bf16x8 __attribute__((ext_vector_type(8)));
typedef __bf16 bf16x4 __attribute__((ext_vector_type(4)));
typedef float  f32x4  __attribute__((ext_vector_type(4)));

static __device__ __forceinline__ f32x4 mfma16(bf16x8 a, bf16x8 b, f32x4 c) {
  return __builtin_amdgcn_mfma_f32_16x16x32_bf16(a, b, c, 0, 0, 0);
}

// async 16B/lane global->LDS; LDS dest = wave-uniform base + lane*16
static __device__ __forceinline__ void load16_lds(const void* g, void* l) {
  __builtin_amdgcn_global_load_lds(
      (const __attribute__((address_space(1))) unsigned int*)g,
      (__attribute__((address_space(3))) unsigned int*)l, 16, 0, 0);
}

// ---------------------------------------------------------------------------
// fused cvt: blocks [0,4096) convert x (fp32->bf16, 8/thread);
// blocks [4096,6144) convert weights: wq (scaled by 0.125*log2e) -> wqk[0],
// wk -> wqk[1MB], wv -> wvb, wo -> wob.
// ---------------------------------------------------------------------------
__global__ __launch_bounds__(256) void cvt_all(
    const float* __restrict__ x,
    const float* __restrict__ w0, const float* __restrict__ w1,
    const float* __restrict__ w2, const float* __restrict__ w3,
    __bf16* __restrict__ xb, __bf16* __restrict__ wqk,
    __bf16* __restrict__ wvb, __bf16* __restrict__ wob) {
  const int blk = blockIdx.x;
  const int t = threadIdx.x;
  if (blk < 4096) {
    int i = blk * 256 + t;
    const float4* in4 = (const float4*)x;
    float4 a = in4[2 * i], b = in4[2 * i + 1];
    __bf16 v[8];
    v[0] = (__bf16)a.x; v[1] = (__bf16)a.y; v[2] = (__bf16)a.z; v[3] = (__bf16)a.w;
    v[4] = (__bf16)b.x; v[5] = (__bf16)b.y; v[6] = (__bf16)b.z; v[7] = (__bf16)b.w;
    *(bf16x8*)(xb + 8 * i) = *(bf16x8*)v;
  } else {
    int b2 = blk - 4096;               // 2048 blocks, 512 per matrix
    int m = b2 >> 9;
    const float* src = (m == 0) ? w0 : (m == 1) ? w1 : (m == 2) ? w2 : w3;
    __bf16* dst = (m == 0) ? wqk : (m == 1) ? (wqk + (size_t)(1024 * 1024))
                : (m == 2) ? wvb : wob;
    const float scl = (m == 0) ? 0.18033688011112042f : 1.0f;  // 0.125*log2(e)
    int i = (b2 & 511) * 256 + t;
    const float4* in4 = (const float4*)src;
    float4 a = in4[2 * i], b = in4[2 * i + 1];
    __bf16 v[8];
    v[0] = (__bf16)(a.x * scl); v[1] = (__bf16)(a.y * scl);
    v[2] = (__bf16)(a.z * scl); v[3] = (__bf16)(a.w * scl);
    v[4] = (__bf16)(b.x * scl); v[5] = (__bf16)(b.y * scl);
    v[6] = (__bf16)(b.z * scl); v[7] = (__bf16)(b.w * scl);
    *(bf16x8*)(dst + 8 * i) = *(bf16x8*)v;
  }
}

// ---------------------------------------------------------------------------
// stage unit: 64 rows x 64 cols bf16 (8 KB) = 1 global_load_lds / thread
// (512-thread kernels), chunk-XOR swizzle (16B chunk c of row r -> c^(r&7)).
// ---------------------------------------------------------------------------
static __device__ __forceinline__ void stage_unit(
    const __bf16* __restrict__ X, long grow0, int K, long k0,
    __bf16* lds, int t) {
  const int lane = t & 63, w = t >> 6;
  const int rl = w * 8 + (lane >> 3);                   // row within unit
  const int chunk = (lane & 7) ^ ((lane >> 3) & 7);     // row&7 == (lane>>3)&7
  load16_lds(X + (grow0 + rl) * (long)K + k0 + chunk * 8,
             lds + (w * 8) * 64);                       // wave-uniform base
}

// ---------------------------------------------------------------------------
// 256x128 triple-buffered 2-phase GEMM core (R10, harness-verified).
// ---------------------------------------------------------------------------
template <typename OutT>
static __device__ __forceinline__ void gemm_core(
    const __bf16* __restrict__ A, const __bf16* __restrict__ Bw,
    OutT* __restrict__ C, int N, int K, long m0, long n0, int t) {
  __shared__ __align__(16) __bf16 As[3][256 * 64];
  __shared__ __align__(16) __bf16 Bs[3][128 * 64];
  const int lane = t & 63, w = t >> 6;
  const int wm = w >> 1, wn = w & 1;        // 4M x 2N waves
  const int l15 = lane & 15, quad = lane >> 4;

  int aoff[4][2], boff[4][2];
#pragma unroll
  for (int mf = 0; mf < 4; mf++)
#pragma unroll
    for (int ks = 0; ks < 2; ks++)
      aoff[mf][ks] = (wm * 64 + mf * 16 + l15) * 64 + (((ks * 4 + quad) ^ (l15 & 7)) << 3);
#pragma unroll
  for (int nf = 0; nf < 4; nf++)
#pragma unroll
    for (int ks = 0; ks < 2; ks++)
      boff[nf][ks] = (wn * 64 + nf * 16 + l15) * 64 + (((ks * 4 + quad) ^ (l15 & 7)) << 3);

  const int NT = K >> 6;
  __bf16 *Ac = As[0], *An = As[1], *Asg = As[2];
  __bf16 *Bc = Bs[0], *Bn = Bs[1], *Bsg = Bs[2];

#pragma unroll
  for (int u = 0; u < 4; u++) stage_unit(A, m0 + u * 64, K, 0, Ac + u * 64 * 64, t);
#pragma unroll
  for (int u = 0; u < 2; u++) stage_unit(Bw, n0 + u * 64, K, 0, Bc + u * 64 * 64, t);
#pragma unroll
  for (int u = 0; u < 4; u++) stage_unit(A, m0 + u * 64, K, 64, An + u * 64 * 64, t);
#pragma unroll
  for (int u = 0; u < 2; u++) stage_unit(Bw, n0 + u * 64, K, 64, Bn + u * 64 * 64, t);
  asm volatile("s_waitcnt vmcnt(6)" ::: "memory");
  __builtin_amdgcn_s_barrier();

  f32x4 acc[4][4] = {};
  for (int T = 0; T < NT; T++) {
    const bool pf2 = (T + 2 < NT);
    const long kn2 = (long)(T + 2) * 64;

    bf16x8 bfr[4][2];
#pragma unroll
    for (int nf = 0; nf < 4; nf++)
#pragma unroll
      for (int ks = 0; ks < 2; ks++)
        bfr[nf][ks] = *(const bf16x8*)(Bc + boff[nf][ks]);
    {
      bf16x8 a00 = *(const bf16x8*)(Ac + aoff[0][0]);
      bf16x8 a01 = *(const bf16x8*)(Ac + aoff[0][1]);
      bf16x8 a10 = *(const bf16x8*)(Ac + aoff[1][0]);
      bf16x8 a11 = *(const bf16x8*)(Ac + aoff[1][1]);
      if (pf2) {
#pragma unroll
        for (int u = 0; u < 4; u++)
          stage_unit(A, m0 + u * 64, K, kn2, Asg + u * 64 * 64, t);
      }
      __builtin_amdgcn_s_barrier();
      asm volatile("s_waitcnt lgkmcnt(0)" ::: "memory");
      __builtin_amdgcn_sched_barrier(0);
      __builtin_amdgcn_s_setprio(1);
#pragma unroll
      for (int nf = 0; nf < 4; nf++) {
        acc[0][nf] = mfma16(a00, bfr[nf][0], acc[0][nf]);
        acc[0][nf] = mfma16(a01, bfr[nf][1], acc[0][nf]);
        acc[1][nf] = mfma16(a10, bfr[nf][0], acc[1][nf]);
        acc[1][nf] = mfma16(a11, bfr[nf][1], acc[1][nf]);
      }
      __builtin_amdgcn_s_setprio(0);
      __builtin_amdgcn_s_barrier();
    }
    {
      bf16x8 a00 = *(const bf16x8*)(Ac + aoff[2][0]);
      bf16x8 a01 = *(const bf16x8*)(Ac + aoff[2][1]);
      bf16x8 a10 = *(const bf16x8*)(Ac + aoff[3][0]);
      bf16x8 a11 = *(const bf16x8*)(Ac + aoff[3][1]);
      if (pf2) {
#pragma unroll
        for (int u = 0; u < 2; u++)
          stage_unit(Bw, n0 + u * 64, K, kn2, Bsg + u * 64 * 64, t);
        asm volatile("s_waitcnt vmcnt(6)" ::: "memory");
      } else {
        asm volatile("s_waitcnt vmcnt(0)" ::: "memory");
      }
      __builtin_amdgcn_s_barrier();
      asm volatile("s_waitcnt lgkmcnt(0)" ::: "memory");
      __builtin_amdgcn_sched_barrier(0);
      __builtin_amdgcn_s_setprio(1);
#pragma unroll
      for (int nf = 0; nf < 4; nf++) {
        acc[2][nf] = mfma16(a00, bfr[nf][0], acc[2][nf]);
        acc[2][nf] = mfma16(a01, bfr[nf][1], acc[2][nf]);
        acc[3][nf] = mfma16(a10, bfr[nf][0], acc[3][nf]);
        acc[3][nf] = mfma16(a11, bfr[nf][1], acc[3][nf]);
      }
      __builtin_amdgcn_s_setprio(0);
      __builtin_amdgcn_s_barrier();
    }
    __bf16* ta = Ac; Ac = An; An = Asg; Asg = ta;
    __bf16* tb = Bc; Bc = Bn; Bn = Bsg; Bsg = tb;
  }

#pragma unroll
  for (int mf = 0; mf < 4; mf++)
#pragma unroll
    for (int nf = 0; nf < 4; nf++)
#pragma unroll
      for (int r = 0; r < 4; r++) {
        long row = m0 + wm * 64 + mf * 16 + quad * 4 + r;
        long col = n0 + wn * 64 + nf * 16 + l15;
        float v = acc[mf][nf][r];
        if constexpr (sizeof(OutT) == 2) C[row * (long)N + col] = (OutT)(__bf16)v;
        else                             C[row * (long)N + col] = v;
      }
}

// merged QK-proj (512 tiles) + V^T-proj (256 tiles): 768 blocks = 3 rounds
__global__ __launch_bounds__(512, 2) void gemm_dual(
    const __bf16* __restrict__ xb, const __bf16* __restrict__ wqk,
    const __bf16* __restrict__ wvb,
    __bf16* __restrict__ QK, __bf16* __restrict__ VTg) {
  const int bid = blockIdx.x;
  const int swz = (bid & 7) * 96 + (bid >> 3);   // bijective over 768
  if (swz < 512) {
    gemm_core<__bf16>(xb, wqk, QK, 2048, 1024,
                      (long)(swz / 16) * 256, (long)(swz % 16) * 128, threadIdx.x);
  } else {
    const int s = swz - 512;
    gemm_core<__bf16>(wvb, xb, VTg, 8192, 1024,
                      (long)(s / 64) * 256, (long)(s % 64) * 128, threadIdx.x);
  }
}

// O-projection (fp32 out), 256 blocks = 1 exact round
__global__ __launch_bounds__(512, 2) void gemm_bt8(
    const __bf16* __restrict__ A, const __bf16* __restrict__ Bw,
    float* __restrict__ C, int M, int N, int K, int NX) {
  const int bid = blockIdx.x;
  const int cpx = gridDim.x >> 3;
  const int swz = (bid & 7) * cpx + (bid >> 3);
  gemm_core<float>(A, Bw, C, N, K, (long)(swz / NX) * 256, (long)(swz % NX) * 128,
                   threadIdx.x);
}

// ---------------------------------------------------------------------------
// Causal attention (attn6, R16 verified 62.1 us): 8 waves / 512 threads,
// sequential paired 256-row halves (qb, 7-qb) -> uniform 36 tiles/block;
// 256 blocks = 1/CU. Triple-buffered K/VT, counted vmcnt(2) (2 loads per
// thread per tile, issued 2 tiles ahead); XCD grouping via bid&7.
// ---------------------------------------------------------------------------
__global__ __launch_bounds__(512, 2) void attn6(
    const __bf16* __restrict__ QK, const __bf16* __restrict__ VT,
    __bf16* __restrict__ O) {
  constexpr int SD = 2048;
  constexpr int LDP = 72;
  __shared__ __align__(16) __bf16 Ks[3][64 * 64];
  __shared__ __align__(16) __bf16 Vs[3][64 * 64];
  __shared__ __align__(16) __bf16 Pw[8 * 32 * LDP];
  const int t = threadIdx.x;
  const int lane = t & 63, w = t >> 6;      // 8 waves
  const int l15 = lane & 15, quad = lane >> 4;

  // bijective decode: a=bid&7 (XCD), jj=(bid>>3)&3 (pair), c=bid>>5 ->
  // g = a*8+c: all 4 pair-blocks of (h,b) share XCD a.
  const int bid = blockIdx.x;
  const int g = (bid & 7) * 8 + (bid >> 5);
  const int jj = (bid >> 3) & 3;
  const int h = g & 15, b = g >> 4;

  const long qbase = (long)b * 2048 * SD + h * 64;
  const long kbase = qbase + 1024;
  __bf16* Pme = Pw + w * 32 * LDP;

  // staging (512 threads): row sr = t>>3 covers all 64 rows; 1 load/thread
  const int sr = t >> 3;
  const int scg = (t & 7) ^ (sr & 7);
  const int ldsOff = (w * 8) * 64;
  const __bf16* gK = QK + kbase + (long)sr * SD + scg * 8;
  const __bf16* gV = VT + (long)(h * 64 + sr) * 8192 + b * 2048 + scg * 8;

  int kvoff[4][2];
#pragma unroll
  for (int nt = 0; nt < 4; nt++)
#pragma unroll
    for (int kk = 0; kk < 2; kk++)
      kvoff[nt][kk] = (nt * 16 + l15) * 64 + (((kk * 4 + quad) ^ (l15 & 7)) << 3);

  bf16x8 ones;
#pragma unroll
  for (int j = 0; j < 8; j++) ones[j] = (__bf16)1.0f;

#pragma unroll
  for (int half = 0; half < 2; half++) {
    const int qb = half ? (7 - jj) : jj;
    const int q0 = qb * 256;
    const int wrow0 = q0 + w * 32;          // 8 waves x 32 rows = 256 rows

    bf16x8 qf[2][2];
#pragma unroll
    for (int mt = 0; mt < 2; mt++)
#pragma unroll
      for (int kk = 0; kk < 2; kk++)
        qf[mt][kk] = *(const bf16x8*)(QK + qbase +
            (long)(wrow0 + mt * 16 + l15) * SD + kk * 32 + quad * 8);

    f32x4 o_acc[2][4] = {};
    f32x4 o_l[2] = {};

    const int nkt = 4 * qb + 4;             // >= 4 always

    // protect buffers from previous half's readers, then stage tiles 0,1
    __syncthreads();
    load16_lds(gK, Ks[0] + ldsOff);
    load16_lds(gV, Vs[0] + ldsOff);
    load16_lds(gK + (long)64 * SD, Ks[1] + ldsOff);
    load16_lds(gV + 64, Vs[1] + ldsOff);

    int cur = 0;
    for (int kt = 0; kt < nkt; kt++) {
      // retire tile kt's 2 loads (issued 2 tiles ago); publish via barrier
      if (kt + 1 < nkt) asm volatile("s_waitcnt vmcnt(2)" ::: "memory");
      else              asm volatile("s_waitcnt vmcnt(0)" ::: "memory");
      __builtin_amdgcn_s_barrier();
      __builtin_amdgcn_sched_barrier(0);

      if (kt + 2 < nkt) {   // prefetch kt+2 into buf (cur+2)%3 (dead)
        int stg = cur + 2; if (stg >= 3) stg -= 3;
        load16_lds(gK + (long)(kt + 2) * 64 * SD, Ks[stg] + ldsOff);
        load16_lds(gV + (kt + 2) * 64, Vs[stg] + ldsOff);
      }

      const int k0 = kt * 64;
      if (k0 <= wrow0 + 31) {
        const __bf16* KsB = Ks[cur];
        const __bf16* VsB = Vs[cur];
        bf16x8 kf[4][2];
#pragma unroll
        for (int nt = 0; nt < 4; nt++)
#pragma unroll
          for (int kk = 0; kk < 2; kk++)
            kf[nt][kk] = *(const bf16x8*)(KsB + kvoff[nt][kk]);
        f32x4 st[4][2];
        __builtin_amdgcn_s_setprio(1);
#pragma unroll
        for (int nt = 0; nt < 4; nt++)
#pragma unroll
          for (int mt = 0; mt < 2; mt++) {
            f32x4 z = {0.f, 0.f, 0.f, 0.f};
            z = mfma16(kf[nt][0], qf[mt][0], z);
            st[nt][mt] = mfma16(kf[nt][1], qf[mt][1], z);
          }
        __builtin_amdgcn_s_setprio(0);

        if (k0 + 63 <= wrow0) {        // fully unmasked tile
#pragma unroll
          for (int mt = 0; mt < 2; mt++)
#pragma unroll
            for (int nt = 0; nt < 4; nt++) {
              bf16x4 pb;
#pragma unroll
              for (int r = 0; r < 4; r++)
                pb[r] = (__bf16)__builtin_amdgcn_exp2f(st[nt][mt][r]);
              *(bf16x4*)(Pme + (mt * 16 + l15) * LDP + nt * 16 + quad * 4) = pb;
            }
        } else {                       // diagonal tile: causal mask
#pragma unroll
          for (int mt = 0; mt < 2; mt++) {
            const int qrow = wrow0 + mt * 16 + l15;
#pragma unroll
            for (int nt = 0; nt < 4; nt++) {
              const int keyb = k0 + nt * 16 + quad * 4;
              bf16x4 pb;
#pragma unroll
              for (int r = 0; r < 4; r++) {
                float e = __builtin_amdgcn_exp2f(st[nt][mt][r]);
                if (keyb + r > qrow) e = 0.f;
                pb[r] = (__bf16)e;
              }
              *(bf16x4*)(Pme + (mt * 16 + l15) * LDP + nt * 16 + quad * 4) = pb;
            }
          }
        }

#pragma unroll
        for (int kk = 0; kk < 2; kk++) {
          bf16x8 vf[4];
#pragma unroll
          for (int dt = 0; dt < 4; dt++)
            vf[dt] = *(const bf16x8*)(VsB + kvoff[dt][kk]);
#pragma unroll
          for (int mt = 0; mt < 2; mt++) {
            bf16x8 pf = *(const bf16x8*)(Pme + (mt * 16 + l15) * LDP + kk * 32 + quad * 8);
            __builtin_amdgcn_s_setprio(1);
#pragma unroll
            for (int dt = 0; dt < 4; dt++)
              o_acc[mt][dt] = mfma16(pf, vf[dt], o_acc[mt][dt]);
            o_l[mt] = mfma16(pf, ones, o_l[mt]);
            __builtin_amdgcn_s_setprio(0);
          }
        }
      }
      cur = (cur == 2) ? 0 : cur + 1;
    }

    // epilogue: o_l holds per-row l in the exact o_acc row layout
#pragma unroll
    for (int mt = 0; mt < 2; mt++) {
#pragma unroll
      for (int r = 0; r < 4; r++) {
        float inv = 1.f / o_l[mt][r];
        int row = wrow0 + mt * 16 + quad * 4 + r;
        long ob = ((long)b * 2048 + row) * 1024 + h * 64;
#pragma unroll
        for (int dt = 0; dt < 4; dt++)
          O[ob + dt * 16 + l15] = (__bf16)(o_acc[mt][dt][r] * inv);
      }
    }
  }
}

// ---------------------------------------------------------------------------
extern "C" void kernel_launch(void* const* d_in, const int* in_sizes, int n_in,
                              void* d_out, int out_size, void* d_ws, size_t ws_size,
                              hipStream_t stream) {
  const float* x  = (const float*)d_in[0];
  const float* wq = (const float*)d_in[1];
  const float* wk = (const float*)d_in[2];
  const float* wv = (const float*)d_in[3];
  const float* wo = (const float*)d_in[4];
  float* out = (float*)d_out;

  char* ws = (char*)d_ws;
  __bf16* xb   = (__bf16*)(ws);               // 16 MB [8192,1024]; reused as Ab
  __bf16* wqk  = (__bf16*)(ws + (16l << 20)); //  4 MB [2048,1024] (wq,wk)
  __bf16* wvb  = (__bf16*)(ws + (20l << 20)); //  2 MB [1024,1024]
  __bf16* wob  = (__bf16*)(ws + (22l << 20)); //  2 MB [1024,1024]
  __bf16* QK   = (__bf16*)(ws + (24l << 20)); // 32 MB [8192,2048]
  __bf16* VTg  = (__bf16*)(ws + (56l << 20)); // 16 MB [1024,8192] -> 72 MB total
  __bf16* Ab   = xb;                          // x dead after both input gemms

  // fused conversions (x + all 4 weights), one launch
  cvt_all<<<6144, 256, 0, stream>>>(x, wq, wk, wv, wo, xb, wqk, wvb, wob);

  // merged QK projection + V^T projection (768 blocks = 3 exact rounds)
  gemm_dual<<<768, 512, 0, stream>>>(xb, wqk, wvb, QK, VTg);

  // causal attention (256 blocks x 512 threads, paired halves, XCD-grouped) -> Ab
  attn6<<<256, 512, 0, stream>>>(QK, VTg, Ab);

  // output projection (fp32 out)              (32x8 = 256 blocks, 1 exact round)
  gemm_bt8<<<256, 512, 0, stream>>>(Ab, wob, out, 8192, 1024, 1024, 8);
}